// Round 13
// baseline (312.965 us; speedup 1.0000x reference)
//
#include <hip/hip_runtime.h>

#define NN 20000
#define DD 128
#define HH 128
#define G4 512
#define DEG 32
#define NPB 32     // nodes per pair: 2 MFMA groups of 16
#define PAIRS 625  // NN/NPB
#define GRID2 512  // exactly 2 blocks/CU resident; extra pairs work-stolen

typedef __attribute__((ext_vector_type(4))) float f32x4;
typedef __attribute__((ext_vector_type(8))) short s16x8;

#ifndef __has_builtin
#define __has_builtin(x) 0
#endif

__device__ int g_cnt;   // next pair index for work stealing; re-armed by k_hp each launch

// rcp builtin (round-9 lesson: raw inline-asm trans ops corrupt — builtins only)
static __device__ __forceinline__ float frcp(float x){
#if __has_builtin(__builtin_amdgcn_rcpf)
  return __builtin_amdgcn_rcpf(x);
#else
  return 1.f/x;
#endif
}

// packed f32x2 -> bf16x2 (RNE) — VOP3, no trans hazard; proven since round 1
static __device__ __forceinline__ unsigned cvt_pk_bf16(float lo, float hi){
  unsigned r;
  asm("v_cvt_pk_bf16_f32 %0, %1, %2" : "=v"(r) : "v"(lo), "v"(hi));
  return r;
}
static __device__ __forceinline__ s16x8 ld8bf(const float* __restrict__ p){
  f32x4 a = *(const f32x4*)p;
  f32x4 b = *(const f32x4*)(p+4);
  union{unsigned u[4]; s16x8 v;} z;
  z.u[0]=cvt_pk_bf16(a[0],a[1]);
  z.u[1]=cvt_pk_bf16(a[2],a[3]);
  z.u[2]=cvt_pk_bf16(b[0],b[1]);
  z.u[3]=cvt_pk_bf16(b[2],b[3]);
  return z.v;
}
// scaled variant: multiply by s before bf16 conversion (gate-halving pre-scale)
static __device__ __forceinline__ s16x8 ld8bf_s(const float* __restrict__ p, float s){
  f32x4 a = *(const f32x4*)p;
  f32x4 b = *(const f32x4*)(p+4);
  union{unsigned u[4]; s16x8 v;} z;
  z.u[0]=cvt_pk_bf16(a[0]*s,a[1]*s);
  z.u[1]=cvt_pk_bf16(a[2]*s,a[3]*s);
  z.u[2]=cvt_pk_bf16(b[0]*s,b[1]*s);
  z.u[3]=cvt_pk_bf16(b[2]*s,b[3]*s);
  return z.v;
}
// bf16 packed in u32 -> f32 (bf16 in high 16 bits IS the f32 bit pattern)
static __device__ __forceinline__ float lo16f(unsigned u){
  union{unsigned x; float f;} v; v.x = u << 16; return v.f;
}
static __device__ __forceinline__ float hi16f(unsigned u){
  union{unsigned x; float f;} v; v.x = u & 0xffff0000u; return v.f;
}

// ---- Eigen/XLA fast-tanh rational (Padé 13/6), error < 1e-6 on the clamped range ----
#define TC_L 7.90531110763549805f
static __device__ __forceinline__ float clampT(float x){   // v_med3_f32
  return fminf(fmaxf(x,-TC_L),TC_L);
}
// returns p = z*P(z^2); sets q = Q(z^2); tanh(z) = p/q
static __device__ __forceinline__ float tanh_pq(float z, float& q){
  float s=z*z;
  float p = __builtin_fmaf(s, -2.76076847742355e-16f, 2.00018790482477e-13f);
  p = __builtin_fmaf(s, p, -8.60467152213735e-11f);
  p = __builtin_fmaf(s, p, 5.12229709037114e-08f);
  p = __builtin_fmaf(s, p, 1.48572235717979e-05f);
  p = __builtin_fmaf(s, p, 6.37261928875436e-04f);
  p = __builtin_fmaf(s, p, 4.89352455891786e-03f);
  p *= z;
  float qq = __builtin_fmaf(s, 1.19825839466702e-06f, 1.18534705686654e-04f);
  qq = __builtin_fmaf(s, qq, 2.26843463243900e-03f);
  qq = __builtin_fmaf(s, qq, 4.89352518554385e-03f);
  q = qq;
  return p;
}

// ---------------- Phase 1: Hp = (h @ W_ih^T + b_ih + b_hh) * S[gate], bf16 ----------------
// PERMUTED layout: element (n, gatecol=128g+16w+4hi+r) stored at n*512 + w*64 + hi*16 + g*4 + r.
// PRE-SCALED by S = {1/2, 1/2, 1, 1/2}: sigmoid gates need x/2 for the tanh identity
// sig(x) = (1 + tanh(x/2))/2; the g-gate feeds tanh directly (plain).
#define SCI 0.5f
#define SCG 1.0f
__global__ __launch_bounds__(512,2) void k_hp(
    const float* __restrict__ h, const float* __restrict__ W_ih,
    const float* __restrict__ b_ih, const float* __restrict__ b_hh,
    unsigned short* __restrict__ Hp)
{
  if(blockIdx.x==0 && threadIdx.x==0) g_cnt = GRID2;  // arm the k_lstm work-steal counter
  const int tid=threadIdx.x, w=tid>>6, lane=tid&63, lo=lane&15, hi=lane>>4;
  const float SC[4]={SCI,SCI,SCG,SCI};
  s16x8 A[4][4];
#pragma unroll
  for(int g=0;g<4;++g){
    const float* wr=W_ih+(size_t)(128*g+16*w+lo)*DD+8*hi;
#pragma unroll
    for(int c=0;c<4;++c) A[g][c]=ld8bf_s(wr+32*c, SC[g]);
  }
  f32x4 bb[4];
#pragma unroll
  for(int g=0;g<4;++g){
    const int gcb=128*g+16*w+4*hi;
    bb[g]=(*(const f32x4*)(b_ih+gcb) + *(const f32x4*)(b_hh+gcb))*SC[g];
  }
  // grid 256, blocks 0..56 take a second 64-node chunk (313 chunks total)
  const int nchunk = (blockIdx.x < 57) ? 2 : 1;
  for(int cc=0; cc<nchunk; ++cc){
    const int n0 = ((cc? 256+blockIdx.x : blockIdx.x))*64;
    f32x4 acc[4][4];
#pragma unroll
    for(int g=0;g<4;++g)
#pragma unroll
      for(int nt=0;nt<4;++nt) acc[g][nt]=(f32x4)0.f;
#pragma unroll
    for(int c=0;c<4;++c){
      s16x8 B[4];
#pragma unroll
      for(int nt=0;nt<4;++nt){
        int nd=n0+16*nt+lo; if(nd>=NN) nd=NN-1;
        B[nt]=ld8bf(h+(size_t)nd*DD+32*c+8*hi);
      }
#pragma unroll
      for(int g=0;g<4;++g)
#pragma unroll
        for(int nt=0;nt<4;++nt)
          acc[g][nt]=__builtin_amdgcn_mfma_f32_16x16x32_bf16(A[g][c],B[nt],acc[g][nt],0,0,0);
    }
#pragma unroll
    for(int nt=0;nt<4;++nt){
      int nd=n0+16*nt+lo;
      if(nd<NN){
        unsigned short* p = Hp + (size_t)nd*G4 + w*64 + hi*16;
        uint4 q0, q1;
        q0.x=cvt_pk_bf16(acc[0][nt][0]+bb[0][0], acc[0][nt][1]+bb[0][1]);
        q0.y=cvt_pk_bf16(acc[0][nt][2]+bb[0][2], acc[0][nt][3]+bb[0][3]);
        q0.z=cvt_pk_bf16(acc[1][nt][0]+bb[1][0], acc[1][nt][1]+bb[1][1]);
        q0.w=cvt_pk_bf16(acc[1][nt][2]+bb[1][2], acc[1][nt][3]+bb[1][3]);
        q1.x=cvt_pk_bf16(acc[2][nt][0]+bb[2][0], acc[2][nt][1]+bb[2][1]);
        q1.y=cvt_pk_bf16(acc[2][nt][2]+bb[2][2], acc[2][nt][3]+bb[2][3]);
        q1.z=cvt_pk_bf16(acc[3][nt][0]+bb[3][0], acc[3][nt][1]+bb[3][1]);
        q1.w=cvt_pk_bf16(acc[3][nt][2]+bb[3][2], acc[3][nt][3]+bb[3][3]);
        *(uint4*)p = q0;
        *(uint4*)(p+8) = q1;
      }
    }
  }
}

// unpack one lane's 32B Hp chunk into the 4-gate accumulator init
static __device__ __forceinline__ void unpack_acc(const uint4 q[2], f32x4 acc[4]){
  acc[0][0]=lo16f(q[0].x); acc[0][1]=hi16f(q[0].x); acc[0][2]=lo16f(q[0].y); acc[0][3]=hi16f(q[0].y);
  acc[1][0]=lo16f(q[0].z); acc[1][1]=hi16f(q[0].z); acc[1][2]=lo16f(q[0].w); acc[1][3]=hi16f(q[0].w);
  acc[2][0]=lo16f(q[1].x); acc[2][1]=hi16f(q[1].x); acc[2][2]=lo16f(q[1].y); acc[2][3]=hi16f(q[1].y);
  acc[3][0]=lo16f(q[1].z); acc[3][1]=hi16f(q[1].z); acc[3][2]=lo16f(q[1].w); acc[3][3]=hi16f(q[1].w);
}

// LSTM cell — TRANS-MINIMIZED: rational tanh for all gates, 3 rcp + 0 exp per element
// (was 5 exp2 + 3 rcp). Diagnostic for the per-CU trans-unit-saturation theory.
//   sig(x) = (1+tanh(x/2))/2; acc holds {i/2, f/2, g, o/2} via the k_hp/W_hh prescale.
//   sig(i)*tanh(g) = (qi+pi)*pg * rcp(2*qi*qg)        [shared denominator, 1 rcp]
//   c      = fma((qf+pf)*rcp(2*qf), c_old, itg)       [1 rcp]
//   h      = (qo+po)*pc * rcp(2*qo*qc)                [1 rcp]
static __device__ __forceinline__ void cell_update(const f32x4 acc[4], float C[4],
                                                   char* wb, int waddr){
  float hv[4];
#pragma unroll
  for(int r=0;r<4;++r){
    float qi,qf,qg,qo,qc;
    float pi=tanh_pq(clampT(acc[0][r]),qi);
    float pf=tanh_pq(clampT(acc[1][r]),qf);
    float pg=tanh_pq(clampT(acc[2][r]),qg);
    float po=tanh_pq(clampT(acc[3][r]),qo);
    float itg=(qi+pi)*pg*frcp(2.f*qi*qg);
    float cc=__builtin_fmaf((qf+pf)*frcp(2.f*qf), C[r], itg);
    C[r]=cc;
    float pc=tanh_pq(clampT(cc),qc);
    hv[r]=(qo+po)*pc*frcp(2.f*qo*qc);
  }
  uint2 pk;
  pk.x=cvt_pk_bf16(hv[0],hv[1]);
  pk.y=cvt_pk_bf16(hv[2],hv[3]);
  *(uint2*)(wb + waddr) = pk;
}

// ---------------- Phase 2: LSTM scan — one-barrier-per-t interior + work-steal (r12) -----
// Grid = 512 (2 blocks/CU). Per t both group-phases in ONE barrier interval
// (parity-double-buffered hpd). Gathers pipelined one phase ahead via renamed qA/qB
// (vmcnt spans barrier). Blocks steal pairs 512..624 from a device atomic.
__global__ __launch_bounds__(512,2) void k_lstm(
    const float* __restrict__ h, const int* __restrict__ nbr,
    const float* __restrict__ W_hh, const unsigned short* __restrict__ Hp,
    const float* __restrict__ W_out, const float* __restrict__ b_out,
    float* __restrict__ out)
{
  __shared__ unsigned short hpd[2][2][16*HH];  // 16 KB: [group][t-parity][16 nodes x 128 dims]
  __shared__ int nlds[DEG*NPB];                // transposed: nlds[t][node] = nbr_idx*G4, 4 KB
  __shared__ int spair;
  const int tid=threadIdx.x, w=tid>>6, lane=tid&63, lo=lane&15, hi=lane>>4;
  const int swz=(lo&7)<<4;
  const int woff=w*64+hi*16;                   // lane's Hp chunk offset (shorts)
  const int waddr=((lo*256 + 32*w + 8*hi) ^ swz);
  const float SC[4]={SCI,SCI,SCG,SCI};

  s16x8 A[4][4];                               // W_hh fragments (prescaled), 64 VGPR
#pragma unroll
  for(int g=0;g<4;++g){
    const float* wr=W_hh+(size_t)(128*g+16*w+lo)*HH+8*hi;
#pragma unroll
    for(int c=0;c<4;++c) A[g][c]=ld8bf_s(wr+32*c, SC[g]);
  }

  int pair = blockIdx.x;
  for(;;){
    const int n0 = pair*NPB;
    {
#pragma unroll
      for(int g=0;g<2;++g){                    // zero read-parity buffers hpd[g][0]
        unsigned* z=(unsigned*)&hpd[g][0][0];
        z[tid]=0u; z[tid+512]=0u;              // 1024 u32 per buffer
      }
#pragma unroll
      for(int i=0;i<2;++i){                    // stage neighbor offsets transposed, pre-scaled
        int idx=tid+512*i;
        nlds[(idx&31)*NPB + (idx>>5)] = nbr[n0*DEG + idx]*G4;
      }
    }
    __syncthreads();

    float cst[2][4]={{0.f,0.f,0.f,0.f},{0.f,0.f,0.f,0.f}};  // plain c-state

    // prologue gather: qA = (t=0, G0)
    uint4 qA[2], qB[2];
    {
      const unsigned short* gp=Hp+(size_t)nlds[lo]+woff;
      qA[0]=*(const uint4*)gp; qA[1]=*(const uint4*)(gp+8);
    }

#define PHASE(g, QUSE, QLOAD, LOFF) { \
    { const unsigned short* gp_=Hp+(size_t)nlds[LOFF]+woff; \
      QLOAD[0]=*(const uint4*)gp_; QLOAD[1]=*(const uint4*)(gp_+8); } \
    s16x8 Bg[4]; \
    const char* rb_=(const char*)&hpd[g][t&1][0]; \
    _Pragma("unroll") \
    for(int c=0;c<4;++c) Bg[c]=*(const s16x8*)(rb_ + (((lo*256 + 64*c + 16*hi)) ^ swz)); \
    f32x4 acc_[4]; \
    unpack_acc(QUSE, acc_); \
    _Pragma("unroll") \
    for(int c=0;c<4;++c) \
      _Pragma("unroll") \
      for(int gg=0;gg<4;++gg) \
        acc_[gg]=__builtin_amdgcn_mfma_f32_16x16x32_bf16(A[gg][c],Bg[c],acc_[gg],0,0,0); \
    cell_update(acc_, cst[g], (char*)&hpd[g][(t+1)&1][0], waddr); }

    for(int t=0;t<DEG;++t){
      const int tn=(t+1<DEG)? t+1 : t;         // clamp: last dummy load re-reads t=31
      PHASE(0, qA, qB, t*NPB + 16 + lo)        // use (t,G0); load (t,G1)
      PHASE(1, qB, qA, tn*NPB + lo)            // use (t,G1); load (t+1,G0)
      asm volatile("s_waitcnt lgkmcnt(0)\n\ts_barrier" ::: "memory");
    }
#undef PHASE

    // ---- fused output projection: out = relu([h, agg] @ W_out^T + b_out) ----
    // agg for group g is in hpd[g][0] (t=31 wrote parity (31+1)&1 = 0).
    s16x8 AO[8];
    {
      const float* wr=W_out+(size_t)(16*w+lo)*256+8*hi;
#pragma unroll
      for(int c=0;c<8;++c) AO[c]=ld8bf(wr+32*c);
    }
    const int ob=16*w+4*hi;
    f32x4 bias=*(const f32x4*)(b_out+ob);
#pragma unroll
    for(int g=0;g<2;++g){
      const int node=n0+g*16+lo;
      s16x8 BB[8];
      const float* hr=h+(size_t)node*DD+8*hi;
#pragma unroll
      for(int c=0;c<4;++c) BB[c]=ld8bf(hr+32*c);
      const char* rb=(const char*)&hpd[g][0][0];
#pragma unroll
      for(int c=0;c<4;++c)
        BB[4+c]=*(const s16x8*)(rb + (((lo*256 + 64*c + 16*hi)) ^ swz));
      f32x4 acc=(f32x4)0.f;
#pragma unroll
      for(int c=0;c<8;++c) acc=__builtin_amdgcn_mfma_f32_16x16x32_bf16(AO[c],BB[c],acc,0,0,0);
#pragma unroll
      for(int r=0;r<4;++r){ float v=acc[r]+bias[r]; acc[r]=v>0.f?v:0.f; }
      *(f32x4*)(out+(size_t)node*HH+ob)=acc;
    }

    // ---- steal the next pair; barrier also protects LDS reuse across pairs ----
    if(tid==0) spair = atomicAdd(&g_cnt, 1);
    __syncthreads();
    pair = spair;
    if(pair >= PAIRS) break;
  }
}

extern "C" void kernel_launch(void* const* d_in, const int* in_sizes, int n_in,
                              void* d_out, int out_size, void* d_ws, size_t ws_size,
                              hipStream_t stream)
{
  const float* h     = (const float*)d_in[0];
  const int*   nbr   = (const int*)d_in[1];
  const float* W_ih  = (const float*)d_in[2];
  const float* W_hh  = (const float*)d_in[3];
  const float* b_ih  = (const float*)d_in[4];
  const float* b_hh  = (const float*)d_in[5];
  const float* W_out = (const float*)d_in[6];
  const float* b_out = (const float*)d_in[7];
  unsigned short* Hp = (unsigned short*)d_ws;   // 20000*512*2B = 20.48 MB

  k_hp<<<256, 512, 0, stream>>>(h, W_ih, b_ih, b_hh, Hp);
  k_lstm<<<GRID2, 512, 0, stream>>>(h, nbr, W_hh, Hp, W_out, b_out, (float*)d_out);
}

// Round 14
// 233.004 us; speedup vs baseline: 1.3432x; 1.3432x over previous
//
#include <hip/hip_runtime.h>

#define NN 20000
#define DD 128
#define HH 128
#define G4 512
#define DEG 32
#define NPB 32     // nodes per pair: 2 MFMA groups of 16
#define PAIRS 625  // NN/NPB
#define GRID2 512  // exactly 2 blocks/CU resident; extra pairs work-stolen

typedef __attribute__((ext_vector_type(4))) float f32x4;
typedef __attribute__((ext_vector_type(2))) float f32x2;
typedef __attribute__((ext_vector_type(8))) short s16x8;

#ifndef __has_builtin
#define __has_builtin(x) 0
#endif

__device__ int g_cnt;   // next pair index for work stealing; re-armed by k_hp each launch

// Builtin transcendentals ONLY (round-9 lesson: raw inline-asm v_exp/v_rcp bypasses
// the compiler's trans-use hazard handling -> numerical corruption).
static __device__ __forceinline__ float fexp2(float x){
#if __has_builtin(__builtin_amdgcn_exp2f)
  return __builtin_amdgcn_exp2f(x);
#else
  return exp2f(x);
#endif
}
static __device__ __forceinline__ float frcp(float x){
#if __has_builtin(__builtin_amdgcn_rcpf)
  return __builtin_amdgcn_rcpf(x);
#else
  return 1.f/x;
#endif
}

// packed f32x2 -> bf16x2 (RNE) — VOP3, no trans hazard; proven since round 1
static __device__ __forceinline__ unsigned cvt_pk_bf16(float lo, float hi){
  unsigned r;
  asm("v_cvt_pk_bf16_f32 %0, %1, %2" : "=v"(r) : "v"(lo), "v"(hi));
  return r;
}
static __device__ __forceinline__ s16x8 ld8bf(const float* __restrict__ p){
  f32x4 a = *(const f32x4*)p;
  f32x4 b = *(const f32x4*)(p+4);
  union{unsigned u[4]; s16x8 v;} z;
  z.u[0]=cvt_pk_bf16(a[0],a[1]);
  z.u[1]=cvt_pk_bf16(a[2],a[3]);
  z.u[2]=cvt_pk_bf16(b[0],b[1]);
  z.u[3]=cvt_pk_bf16(b[2],b[3]);
  return z.v;
}
// scaled variant: multiply by s before bf16 conversion (log2e pre-scaling)
static __device__ __forceinline__ s16x8 ld8bf_s(const float* __restrict__ p, float s){
  f32x4 a = *(const f32x4*)p;
  f32x4 b = *(const f32x4*)(p+4);
  union{unsigned u[4]; s16x8 v;} z;
  z.u[0]=cvt_pk_bf16(a[0]*s,a[1]*s);
  z.u[1]=cvt_pk_bf16(a[2]*s,a[3]*s);
  z.u[2]=cvt_pk_bf16(b[0]*s,b[1]*s);
  z.u[3]=cvt_pk_bf16(b[2]*s,b[3]*s);
  return z.v;
}
// bf16 packed in u32 -> f32 (bf16 in high 16 bits IS the f32 bit pattern)
static __device__ __forceinline__ float lo16f(unsigned u){
  union{unsigned x; float f;} v; v.x = u << 16; return v.f;
}
static __device__ __forceinline__ float hi16f(unsigned u){
  union{unsigned x; float f;} v; v.x = u & 0xffff0000u; return v.f;
}
#define NLOG2E -1.44269504f
#define TLOG2E  2.88539008f

// ---------------- Phase 1: Hp = (h @ W_ih^T + b_ih + b_hh) * S[gate], bf16 ----------------
// PERMUTED layout: element (n, gatecol=128g+16w+4hi+r) stored at n*512 + w*64 + hi*16 + g*4 + r.
// PRE-SCALED by S = {-log2e, -log2e, 2log2e, -log2e} per gate (acc feeds exp2 directly).
__global__ __launch_bounds__(512,2) void k_hp(
    const float* __restrict__ h, const float* __restrict__ W_ih,
    const float* __restrict__ b_ih, const float* __restrict__ b_hh,
    unsigned short* __restrict__ Hp)
{
  if(blockIdx.x==0 && threadIdx.x==0) g_cnt = GRID2;  // arm the k_lstm work-steal counter
  const int tid=threadIdx.x, w=tid>>6, lane=tid&63, lo=lane&15, hi=lane>>4;
  const float SC[4]={NLOG2E,NLOG2E,TLOG2E,NLOG2E};
  s16x8 A[4][4];
#pragma unroll
  for(int g=0;g<4;++g){
    const float* wr=W_ih+(size_t)(128*g+16*w+lo)*DD+8*hi;
#pragma unroll
    for(int c=0;c<4;++c) A[g][c]=ld8bf_s(wr+32*c, SC[g]);
  }
  f32x4 bb[4];
#pragma unroll
  for(int g=0;g<4;++g){
    const int gcb=128*g+16*w+4*hi;
    bb[g]=(*(const f32x4*)(b_ih+gcb) + *(const f32x4*)(b_hh+gcb))*SC[g];
  }
  // grid 256, blocks 0..56 take a second 64-node chunk (313 chunks total)
  const int nchunk = (blockIdx.x < 57) ? 2 : 1;
  for(int cc=0; cc<nchunk; ++cc){
    const int n0 = ((cc? 256+blockIdx.x : blockIdx.x))*64;
    f32x4 acc[4][4];
#pragma unroll
    for(int g=0;g<4;++g)
#pragma unroll
      for(int nt=0;nt<4;++nt) acc[g][nt]=(f32x4)0.f;
#pragma unroll
    for(int c=0;c<4;++c){
      s16x8 B[4];
#pragma unroll
      for(int nt=0;nt<4;++nt){
        int nd=n0+16*nt+lo; if(nd>=NN) nd=NN-1;
        B[nt]=ld8bf(h+(size_t)nd*DD+32*c+8*hi);
      }
#pragma unroll
      for(int g=0;g<4;++g)
#pragma unroll
        for(int nt=0;nt<4;++nt)
          acc[g][nt]=__builtin_amdgcn_mfma_f32_16x16x32_bf16(A[g][c],B[nt],acc[g][nt],0,0,0);
    }
#pragma unroll
    for(int nt=0;nt<4;++nt){
      int nd=n0+16*nt+lo;
      if(nd<NN){
        unsigned short* p = Hp + (size_t)nd*G4 + w*64 + hi*16;
        uint4 q0, q1;
        q0.x=cvt_pk_bf16(acc[0][nt][0]+bb[0][0], acc[0][nt][1]+bb[0][1]);
        q0.y=cvt_pk_bf16(acc[0][nt][2]+bb[0][2], acc[0][nt][3]+bb[0][3]);
        q0.z=cvt_pk_bf16(acc[1][nt][0]+bb[1][0], acc[1][nt][1]+bb[1][1]);
        q0.w=cvt_pk_bf16(acc[1][nt][2]+bb[1][2], acc[1][nt][3]+bb[1][3]);
        q1.x=cvt_pk_bf16(acc[2][nt][0]+bb[2][0], acc[2][nt][1]+bb[2][1]);
        q1.y=cvt_pk_bf16(acc[2][nt][2]+bb[2][2], acc[2][nt][3]+bb[2][3]);
        q1.z=cvt_pk_bf16(acc[3][nt][0]+bb[3][0], acc[3][nt][1]+bb[3][1]);
        q1.w=cvt_pk_bf16(acc[3][nt][2]+bb[3][2], acc[3][nt][3]+bb[3][3]);
        *(uint4*)p = q0;
        *(uint4*)(p+8) = q1;
      }
    }
  }
}

// unpack one lane's 32B Hp chunk into the 4-gate accumulator init
static __device__ __forceinline__ void unpack_acc(const uint4 q[2], f32x4 acc[4]){
  acc[0][0]=lo16f(q[0].x); acc[0][1]=hi16f(q[0].x); acc[0][2]=lo16f(q[0].y); acc[0][3]=hi16f(q[0].y);
  acc[1][0]=lo16f(q[0].z); acc[1][1]=hi16f(q[0].z); acc[1][2]=lo16f(q[0].w); acc[1][3]=hi16f(q[0].w);
  acc[2][0]=lo16f(q[1].x); acc[2][1]=hi16f(q[1].x); acc[2][2]=lo16f(q[1].y); acc[2][3]=hi16f(q[1].y);
  acc[3][0]=lo16f(q[1].z); acc[3][1]=hi16f(q[1].z); acc[3][2]=lo16f(q[1].w); acc[3][3]=hi16f(q[1].w);
}

// LSTM cell, log2-domain prescaled gates, T-domain cell state C = c*2log2e (r10-proven math),
// non-trans arithmetic expressed as f32x2 so hipcc emits v_pk_fma/v_pk_mul/v_pk_add
// (halves plain-VALU issue; trans ops unchanged: 5 exp2 + 3 rcp per element).
static __device__ __forceinline__ void cell_update(const f32x4 acc[4], f32x2 C[2],
                                                   char* wb, int woffc){
  unsigned pkw[2];
#pragma unroll
  for(int p=0;p<2;++p){
    f32x2 ei={fexp2(acc[0][2*p]),fexp2(acc[0][2*p+1])};
    f32x2 ef={fexp2(acc[1][2*p]),fexp2(acc[1][2*p+1])};
    f32x2 eg={fexp2(acc[2][2*p]),fexp2(acc[2][2*p+1])};
    f32x2 eo={fexp2(acc[3][2*p]),fexp2(acc[3][2*p+1])};
    const f32x2 one={1.f,1.f};
    const f32x2 T={TLOG2E,TLOG2E};
    f32x2 pig=(one+ei)*(one+eg);
    f32x2 rig={frcp(pig[0]),frcp(pig[1])};
    f32x2 itgT=(eg*T-T)*rig;
    f32x2 pf=one+ef;
    f32x2 rf={frcp(pf[0]),frcp(pf[1])};
    f32x2 Cn=C[p]*rf+itgT;
    C[p]=Cn;
    f32x2 ec={fexp2(Cn[0]),fexp2(Cn[1])};
    f32x2 den=(one+eo)*(one+ec);
    f32x2 rden={frcp(den[0]),frcp(den[1])};
    f32x2 hv=(ec-one)*rden;
    pkw[p]=cvt_pk_bf16(hv[0],hv[1]);
  }
  uint2 pk; pk.x=pkw[0]; pk.y=pkw[1];
  *(uint2*)(wb+woffc)=pk;
}

// ---------------- Phase 2: LSTM scan — one-barrier-per-t + steal; VALU-port-trimmed -----
// Grid = 512 (2 blocks/CU). t-loop unrolled x2 so buffer parity is a COMPILE-TIME constant:
// all LDS read/write addresses are 4 precomputed lane VGPRs + constant offset immediates
// (zero per-phase address VALU; swz XOR no longer recomputed — it couldn't fold because
// (X+64c)^swz != (X^swz)+64c). nlds holds BYTE offsets (no shorts->bytes shift). Gathers
// pipelined one phase ahead via renamed qA/qB (vmcnt spans the barrier).
__global__ __launch_bounds__(512,2) void k_lstm(
    const float* __restrict__ h, const int* __restrict__ nbr,
    const float* __restrict__ W_hh, const unsigned short* __restrict__ Hp,
    const float* __restrict__ W_out, const float* __restrict__ b_out,
    float* __restrict__ out)
{
  __shared__ unsigned short hpd[2][2][16*HH];  // 16 KB: [group][t-parity][16 nodes x 128 dims]
  __shared__ int nlds[DEG*NPB];                // transposed: nlds[t][node] = nbr_idx*1024 B, 4 KB
  __shared__ int spair;
  const int tid=threadIdx.x, w=tid>>6, lane=tid&63, lo=lane&15, hi=lane>>4;
  const int swz=(lo&7)<<4;
  const float SC[4]={NLOG2E,NLOG2E,TLOG2E,NLOG2E};

  // ---- hoisted lane-invariant addresses (computed ONCE) ----
  const char* lbase=(const char*)&hpd[0][0][0];
  const char* rd0=lbase + ((lo*256 +   0 + 16*hi) ^ swz);
  const char* rd1=lbase + ((lo*256 +  64 + 16*hi) ^ swz);
  const char* rd2=lbase + ((lo*256 + 128 + 16*hi) ^ swz);
  const char* rd3=lbase + ((lo*256 + 192 + 16*hi) ^ swz);
  char* wrp=(char*)lbase + ((lo*256 + 32*w + 8*hi) ^ swz);
  const char* nlp=(const char*)nlds + lo*4;
  const char* hpB=(const char*)Hp + w*128 + hi*32;   // lane's Hp chunk base (bytes)

  s16x8 A[4][4];                               // W_hh fragments (prescaled), 64 VGPR
#pragma unroll
  for(int g=0;g<4;++g){
    const float* wr=W_hh+(size_t)(128*g+16*w+lo)*HH+8*hi;
#pragma unroll
    for(int c=0;c<4;++c) A[g][c]=ld8bf_s(wr+32*c, SC[g]);
  }

  int pair = blockIdx.x;
  for(;;){
    const int n0 = pair*NPB;
    {
      unsigned* z=(unsigned*)&hpd[0][0][0];
      z[tid]=0u; z[tid+512]=0u;                // zero hpd[0][0] (par-0 read buffers, h0=0)
      z[tid+2048]=0u; z[tid+2560]=0u;          // zero hpd[1][0]
#pragma unroll
      for(int i=0;i<2;++i){                    // stage neighbor BYTE offsets transposed
        int idx=tid+512*i;
        nlds[(idx&31)*NPB + (idx>>5)] = nbr[n0*DEG + idx]*(G4*2);
      }
    }
    __syncthreads();

    f32x2 cst[2][2]={{{0.f,0.f},{0.f,0.f}},{{0.f,0.f},{0.f,0.f}}};  // C-state (x 2log2e)

    // prologue gather: qA = (t=0, G0)
    uint4 qA[2], qB[2];
    {
      int no=*(const int*)(nlp);
      const char* gp=hpB+(size_t)(unsigned)no;
      qA[0]=*(const uint4*)gp; qA[1]=*(const uint4*)(gp+16);
    }

// G, PAR are literals -> LDS buffer selection folds into ds_read/ds_write offset immediates.
#define PHASE(G, PAR, QUSE, QLOAD, NLOFF) { \
    { int no_=*(const int*)(nlp + (NLOFF)); \
      const char* gp_=hpB+(size_t)(unsigned)no_; \
      QLOAD[0]=*(const uint4*)gp_; QLOAD[1]=*(const uint4*)(gp_+16); } \
    s16x8 Bg[4]; \
    Bg[0]=*(const s16x8*)(rd0 + ((G)*8192+(PAR)*4096)); \
    Bg[1]=*(const s16x8*)(rd1 + ((G)*8192+(PAR)*4096)); \
    Bg[2]=*(const s16x8*)(rd2 + ((G)*8192+(PAR)*4096)); \
    Bg[3]=*(const s16x8*)(rd3 + ((G)*8192+(PAR)*4096)); \
    f32x4 acc_[4]; \
    unpack_acc(QUSE, acc_); \
    _Pragma("unroll") \
    for(int c=0;c<4;++c) \
      _Pragma("unroll") \
      for(int gg=0;gg<4;++gg) \
        acc_[gg]=__builtin_amdgcn_mfma_f32_16x16x32_bf16(A[gg][c],Bg[c],acc_[gg],0,0,0); \
    cell_update(acc_, cst[G], wrp, ((G)*8192+((PAR)^1)*4096)); }

    for(int k2=0;k2<DEG/2;++k2){
      const int t0=2*k2, t1=2*k2+1;
      const int l1=t0*128+64;                          // (t0,G1)
      const int l2=t1*128;                             // (t1,G0)
      const int l3=t1*128+64;                          // (t1,G1)
      const int l4=((t1+1<DEG)? t1+1 : t1)*128;        // (t2,G0), clamped dummy at end
      PHASE(0,0, qA,qB, l1)
      PHASE(1,0, qB,qA, l2)
      asm volatile("s_waitcnt lgkmcnt(0)\n\ts_barrier" ::: "memory");
      PHASE(0,1, qA,qB, l3)
      PHASE(1,1, qB,qA, l4)
      asm volatile("s_waitcnt lgkmcnt(0)\n\ts_barrier" ::: "memory");
    }
#undef PHASE

    // ---- fused output projection: out = relu([h, agg] @ W_out^T + b_out) ----
    // agg for group g is in hpd[g][0] (t=31 wrote parity 0).
    s16x8 AO[8];
    {
      const float* wr=W_out+(size_t)(16*w+lo)*256+8*hi;
#pragma unroll
      for(int c=0;c<8;++c) AO[c]=ld8bf(wr+32*c);
    }
    const int ob=16*w+4*hi;
    f32x4 bias=*(const f32x4*)(b_out+ob);
#pragma unroll
    for(int g=0;g<2;++g){
      const int node=n0+g*16+lo;
      s16x8 BB[8];
      const float* hr=h+(size_t)node*DD+8*hi;
#pragma unroll
      for(int c=0;c<4;++c) BB[c]=ld8bf(hr+32*c);
      BB[4]=*(const s16x8*)(rd0 + g*8192);
      BB[5]=*(const s16x8*)(rd1 + g*8192);
      BB[6]=*(const s16x8*)(rd2 + g*8192);
      BB[7]=*(const s16x8*)(rd3 + g*8192);
      f32x4 acc=(f32x4)0.f;
#pragma unroll
      for(int c=0;c<8;++c) acc=__builtin_amdgcn_mfma_f32_16x16x32_bf16(AO[c],BB[c],acc,0,0,0);
#pragma unroll
      for(int r=0;r<4;++r){ float v=acc[r]+bias[r]; acc[r]=v>0.f?v:0.f; }
      *(f32x4*)(out+(size_t)node*HH+ob)=acc;
    }

    // ---- steal the next pair; barrier also protects LDS reuse across pairs ----
    if(tid==0) spair = atomicAdd(&g_cnt, 1);
    __syncthreads();
    pair = spair;
    if(pair >= PAIRS) break;
  }
}

extern "C" void kernel_launch(void* const* d_in, const int* in_sizes, int n_in,
                              void* d_out, int out_size, void* d_ws, size_t ws_size,
                              hipStream_t stream)
{
  const float* h     = (const float*)d_in[0];
  const int*   nbr   = (const int*)d_in[1];
  const float* W_ih  = (const float*)d_in[2];
  const float* W_hh  = (const float*)d_in[3];
  const float* b_ih  = (const float*)d_in[4];
  const float* b_hh  = (const float*)d_in[5];
  const float* W_out = (const float*)d_in[6];
  const float* b_out = (const float*)d_in[7];
  unsigned short* Hp = (unsigned short*)d_ws;   // 20000*512*2B = 20.48 MB

  k_hp<<<256, 512, 0, stream>>>(h, W_ih, b_ih, b_hh, Hp);
  k_lstm<<<GRID2, 512, 0, stream>>>(h, nbr, W_hh, Hp, W_out, b_out, (float*)d_out);
}